// Round 8
// baseline (476.962 us; speedup 1.0000x reference)
//
#include <hip/hip_runtime.h>
#include <math.h>

#define T_LEN 256
#define BATCH 32
#define HID   768
#define GH    384   // 3*LSTM_H
#define LH    128   // LSTM_H
#define NLAB  9
#define M_TOT (T_LEN*BATCH)  // 8192

typedef float v2f __attribute__((ext_vector_type(2)));
typedef _Float16 h8 __attribute__((ext_vector_type(8)));
typedef float f4 __attribute__((ext_vector_type(4)));

#define LO_SCALE 1024.f
#define LO_INV   (1.f/1024.f)

// ---------------- K1: xp = emb[ids] @ [Wih_f;Wih_b]^T + bias  (MFMA, frozen) -
__global__ __launch_bounds__(256, 2) void k_gemm_xp(
    const int* __restrict__ ids, const float* __restrict__ emb,
    const float* __restrict__ Wf, const float* __restrict__ Wb,
    const float* __restrict__ bihf, const float* __restrict__ bihb,
    float* __restrict__ xp)
{
  __shared__ __align__(16) _Float16 Ah[128*40];
  __shared__ __align__(16) _Float16 Al[128*40];
  __shared__ __align__(16) _Float16 Bh[128*40];
  __shared__ __align__(16) _Float16 Bl[128*40];

  const int tid  = threadIdx.x;
  const int lane = tid & 63, w = tid >> 6;
  const int m0 = blockIdx.y * 128, n0 = blockIdx.x * 128;

  const int srow = tid >> 1, sk = (tid & 1) * 16;
  const int gm = m0 + srow;
  const int tok = ids[(gm & 31) * T_LEN + (gm >> 5)];
  const float* aG = emb + (size_t)tok * HID + sk;
  const int gn = n0 + srow;
  const float* bG = (gn < GH ? Wf + (size_t)gn * HID
                             : Wb + (size_t)(gn - GH) * HID) + sk;

  const int fr = lane & 15, fq = lane >> 4;
  const int mrow = (w & 1) * 64;
  const int ncol = (w >> 1) * 64;

  f4 acc[4][4];
  f4 acc2[4][4];
#pragma unroll
  for (int i = 0; i < 4; ++i)
#pragma unroll
    for (int j = 0; j < 4; ++j) { acc[i][j] = f4{0,0,0,0}; acc2[i][j] = f4{0,0,0,0}; }

  const int sb = srow * 40 + sk;

  for (int kt = 0; kt < HID / 32; ++kt) {
    __syncthreads();
#pragma unroll
    for (int m = 0; m < 2; ++m) {
      const float* src = m ? (bG + kt * 32) : (aG + kt * 32);
      _Float16* dsth = m ? Bh : Ah;
      _Float16* dstl = m ? Bl : Al;
#pragma unroll
      for (int seg = 0; seg < 2; ++seg) {
        float4 x0 = *reinterpret_cast<const float4*>(src + seg * 8);
        float4 x1 = *reinterpret_cast<const float4*>(src + seg * 8 + 4);
        float xs[8] = {x0.x, x0.y, x0.z, x0.w, x1.x, x1.y, x1.z, x1.w};
        h8 hi, lo;
#pragma unroll
        for (int c = 0; c < 8; ++c) {
          _Float16 h = (_Float16)xs[c];
          hi[c] = h;
          lo[c] = (_Float16)((xs[c] - (float)h) * LO_SCALE);
        }
        *reinterpret_cast<h8*>(&dsth[sb + seg * 8]) = hi;
        *reinterpret_cast<h8*>(&dstl[sb + seg * 8]) = lo;
      }
    }
    __syncthreads();

    h8 fbh[4], fbl[4];
#pragma unroll
    for (int j = 0; j < 4; ++j) {
      const int off = (ncol + j * 16 + fr) * 40 + fq * 8;
      fbh[j] = *reinterpret_cast<const h8*>(&Bh[off]);
      fbl[j] = *reinterpret_cast<const h8*>(&Bl[off]);
    }
#pragma unroll
    for (int i = 0; i < 4; ++i) {
      const int off = (mrow + i * 16 + fr) * 40 + fq * 8;
      h8 fah = *reinterpret_cast<const h8*>(&Ah[off]);
      h8 fal = *reinterpret_cast<const h8*>(&Al[off]);
#pragma unroll
      for (int j = 0; j < 4; ++j) {
        acc[i][j]  = __builtin_amdgcn_mfma_f32_16x16x32_f16(fah, fbh[j], acc[i][j],  0, 0, 0);
        acc2[i][j] = __builtin_amdgcn_mfma_f32_16x16x32_f16(fah, fbl[j], acc2[i][j], 0, 0, 0);
        acc2[i][j] = __builtin_amdgcn_mfma_f32_16x16x32_f16(fal, fbh[j], acc2[i][j], 0, 0, 0);
      }
    }
  }

  float bcol[4];
#pragma unroll
  for (int j = 0; j < 4; ++j) {
    const int c = n0 + ncol + j * 16 + fr;
    bcol[j] = (c < GH) ? bihf[c] : bihb[c - GH];
  }
#pragma unroll
  for (int i = 0; i < 4; ++i)
#pragma unroll
    for (int j = 0; j < 4; ++j) {
      const int col = n0 + ncol + j * 16 + fr;
#pragma unroll
      for (int r = 0; r < 4; ++r) {
        const int row = m0 + mrow + i * 16 + fq * 4 + r;
        xp[(size_t)row * HID + col] = acc[i][j][r] + acc2[i][j][r] * LO_INV + bcol[j];
      }
    }
}

// ---------------- K2: bidirectional GRU recurrence (v3 — frozen) ------------
// (also zeroes lossp for the downstream fused CRF kernel)
__global__ __launch_bounds__(512, 2) void k_gru(
    const float* __restrict__ xp,
    const float* __restrict__ Whhf, const float* __restrict__ Whhb,
    const float* __restrict__ bhhf, const float* __restrict__ bhhb,
    float* __restrict__ hbuf, float* __restrict__ lossp)
{
  __shared__ __align__(16) float hsp[2][144];
  const int tid = threadIdx.x;
  const int g   = tid >> 2;
  const int q   = tid & 3;
  const int bd  = blockIdx.x;
  const int dir = bd >> 5, b = bd & 31;
  const float* Whh = dir ? Whhb : Whhf;
  const float* bhh = dir ? bhhb : bhhf;

  if (bd == 0 && tid == 0) *lossp = 0.f;

  v2f w[3][16];
#pragma unroll
  for (int gate = 0; gate < 3; ++gate) {
    const float* wrow = Whh + (size_t)(gate * LH + g) * LH + q * 32;
#pragma unroll
    for (int j = 0; j < 8; ++j) {
      float4 w4 = *reinterpret_cast<const float4*>(wrow + j * 4);
      w[gate][2*j]   = v2f{w4.x, w4.y};
      w[gate][2*j+1] = v2f{w4.z, w4.w};
    }
  }
  const float br = bhh[g], bz = bhh[g + LH], bn = bhh[g + 2*LH];

  if (tid < LH) hsp[0][36*(tid >> 5) + (tid & 31)] = 0.f;

  const int t0   = dir ? (T_LEN - 1) : 0;
  const int dt   = dir ? -1 : 1;
  const float* xbase = xp + (size_t)b * HID + dir * GH + g;
  float* hob = hbuf + (size_t)b * 256 + dir * LH + g;

  float xr = 0.f, xz = 0.f, xn = 0.f;
  if (q == 0) {
    const float* p = xbase + (size_t)t0 * BATCH * HID;
    xr = p[0]; xz = p[LH]; xn = p[2*LH];
  }
  float hprev = 0.f;
  __syncthreads();

  int t = t0;
  for (int step = 0; step < T_LEN; ++step) {
    const int tn = (step < T_LEN - 1) ? (t + dt) : t;
    float xrn = 0.f, xzn = 0.f, xnn = 0.f;
    if (q == 0) {
      const float* p = xbase + (size_t)tn * BATCH * HID;
      xrn = p[0]; xzn = p[LH]; xnn = p[2*LH];
    }

    const float* hc = &hsp[step & 1][36 * q];
    v2f ar0 = v2f{0.f,0.f}, ar1 = ar0, az0 = ar0, az1 = ar0, an0 = ar0, an1 = ar0;
#pragma unroll
    for (int j = 0; j < 4; ++j) {
      float4 ha = *reinterpret_cast<const float4*>(hc + 8*j);
      float4 hb = *reinterpret_cast<const float4*>(hc + 8*j + 4);
      v2f h0 = v2f{ha.x, ha.y}, h1 = v2f{ha.z, ha.w};
      v2f h2 = v2f{hb.x, hb.y}, h3 = v2f{hb.z, hb.w};
      ar0 = __builtin_elementwise_fma(w[0][4*j+0], h0, ar0);
      ar1 = __builtin_elementwise_fma(w[0][4*j+1], h1, ar1);
      ar0 = __builtin_elementwise_fma(w[0][4*j+2], h2, ar0);
      ar1 = __builtin_elementwise_fma(w[0][4*j+3], h3, ar1);
      az0 = __builtin_elementwise_fma(w[1][4*j+0], h0, az0);
      az1 = __builtin_elementwise_fma(w[1][4*j+1], h1, az1);
      az0 = __builtin_elementwise_fma(w[1][4*j+2], h2, az0);
      az1 = __builtin_elementwise_fma(w[1][4*j+3], h3, az1);
      an0 = __builtin_elementwise_fma(w[2][4*j+0], h0, an0);
      an1 = __builtin_elementwise_fma(w[2][4*j+1], h1, an1);
      an0 = __builtin_elementwise_fma(w[2][4*j+2], h2, an0);
      an1 = __builtin_elementwise_fma(w[2][4*j+3], h3, an1);
    }
    float ar = (ar0.x + ar0.y) + (ar1.x + ar1.y);
    float az = (az0.x + az0.y) + (az1.x + az1.y);
    float an = (an0.x + an0.y) + (an1.x + an1.y);
    ar += __shfl_xor(ar, 1);  ar += __shfl_xor(ar, 2);
    az += __shfl_xor(az, 1);  az += __shfl_xor(az, 2);
    an += __shfl_xor(an, 1);  an += __shfl_xor(an, 2);

    if (q == 0) {
      float r  = __builtin_amdgcn_rcpf(1.f + __expf(-(xr + ar + br)));
      float z  = __builtin_amdgcn_rcpf(1.f + __expf(-(xz + az + bz)));
      float e2 = __expf(2.f * (xn + r * (an + bn)));
      float n  = (e2 - 1.f) * __builtin_amdgcn_rcpf(e2 + 1.f);
      float hnew = (1.f - z) * n + z * hprev;
      hprev = hnew;
      hsp[(step + 1) & 1][36*(g >> 5) + (g & 31)] = hnew;
      hob[(size_t)t * BATCH * 256] = hnew;
    }
    __syncthreads();
    xr = xrn; xz = xzn; xn = xnn;
    t = tn;
  }
}

// ---------------- K3: fused emissions + Viterbi + CRF-LLH -------------------
// 32 blocks (one per batch), 256 threads. Phase 1: all 256x9 emissions into
// LDS el[t*10+j] (Wlin register-resident per 16-lane group, shfl reduce).
// One barrier. Phase 2: wave 0 = Viterbi, wave 1 = LLH, et read from LDS
// with 1-step prefetch (no global loads on the serial chains).
__global__ __launch_bounds__(256, 1) void k_crf_fused(
    const float* __restrict__ hbuf, const float* __restrict__ Wlin,
    const float* __restrict__ blin, const int* __restrict__ labels,
    const float* __restrict__ trans, const float* __restrict__ start,
    const float* __restrict__ endv, float* __restrict__ dec_out,
    float* __restrict__ lossp)
{
  __shared__ float el[T_LEN * 10];
  __shared__ __align__(16) unsigned char bp8[(T_LEN - 1) * 16];
  const int b    = blockIdx.x;
  const int tid  = threadIdx.x;
  const int lane = tid & 63, w = tid >> 6;
  const int sub  = lane >> 4, l16 = lane & 15;

  // Wlin slice for this lane, all 9 labels: 144 VGPRs (occupancy irrelevant:
  // 32 blocks on 256 CUs, 1 wave/SIMD).
  float4 wreg[NLAB][4];
#pragma unroll
  for (int j = 0; j < NLAB; ++j)
#pragma unroll
    for (int c = 0; c < 4; ++c)
      wreg[j][c] = *reinterpret_cast<const float4*>(Wlin + j * 256 + l16 * 16 + c * 4);

  // ---- phase 1: emissions ----
  for (int k = 0; k < 16; ++k) {
    const int t = w * 64 + k * 4 + sub;
    const float* hp = hbuf + ((size_t)t * BATCH + b) * 256 + l16 * 16;
    const float4 h0 = *reinterpret_cast<const float4*>(hp);
    const float4 h1 = *reinterpret_cast<const float4*>(hp + 4);
    const float4 h2 = *reinterpret_cast<const float4*>(hp + 8);
    const float4 h3 = *reinterpret_cast<const float4*>(hp + 12);
    float acc[NLAB];
#pragma unroll
    for (int j = 0; j < NLAB; ++j) {
      const float4 w0 = wreg[j][0], w1 = wreg[j][1], w2 = wreg[j][2], w3 = wreg[j][3];
      float s0 = h0.x*w0.x + h0.y*w0.y + h0.z*w0.z + h0.w*w0.w;
      float s1 = h1.x*w1.x + h1.y*w1.y + h1.z*w1.z + h1.w*w1.w;
      float s2 = h2.x*w2.x + h2.y*w2.y + h2.z*w2.z + h2.w*w2.w;
      float s3 = h3.x*w3.x + h3.y*w3.y + h3.z*w3.z + h3.w*w3.w;
      acc[j] = (s0 + s1) + (s2 + s3);
    }
#pragma unroll
    for (int j = 0; j < NLAB; ++j) {
#pragma unroll
      for (int off = 1; off < 16; off <<= 1)
        acc[j] += __shfl_xor(acc[j], off);
    }
    if (l16 < NLAB) {
      float v = acc[0];
#pragma unroll
      for (int j = 1; j < NLAB; ++j) v = (l16 == j) ? acc[j] : v;
      el[t * 10 + l16] = v + blin[l16];
    }
  }
  __syncthreads();

  if (w == 0) {
    // ---- Viterbi ----
    float tcol[NLAB];
#pragma unroll
    for (int i = 0; i < NLAB; ++i)
      tcol[i] = (lane < NLAB) ? trans[i * NLAB + lane] : 0.f;
    float alpha = (lane < NLAB) ? (start[lane] + el[lane]) : -3e38f;
    float et_next = (lane < NLAB) ? el[10 + lane] : 0.f;
    for (int s = 0; s < T_LEN - 1; ++s) {
      const float et = et_next;
      if (s < T_LEN - 2)
        et_next = (lane < NLAB) ? el[(s + 2) * 10 + lane] : 0.f;
      float v[NLAB];
#pragma unroll
      for (int i = 0; i < NLAB; ++i) v[i] = __shfl(alpha, i) + tcol[i];
      float v01 = (v[0] >= v[1]) ? v[0] : v[1];  int i01 = (v[0] >= v[1]) ? 0 : 1;
      float v23 = (v[2] >= v[3]) ? v[2] : v[3];  int i23 = (v[2] >= v[3]) ? 2 : 3;
      float v45 = (v[4] >= v[5]) ? v[4] : v[5];  int i45 = (v[4] >= v[5]) ? 4 : 5;
      float v67 = (v[6] >= v[7]) ? v[6] : v[7];  int i67 = (v[6] >= v[7]) ? 6 : 7;
      float va = (v01 >= v23) ? v01 : v23;       int ia = (v01 >= v23) ? i01 : i23;
      float vb = (v45 >= v67) ? v45 : v67;       int ib = (v45 >= v67) ? i45 : i67;
      float vc = (va >= vb) ? va : vb;           int ic = (va >= vb) ? ia : ib;
      float best = (vc >= v[8]) ? vc : v[8];     int bi = (vc >= v[8]) ? ic : 8;
      alpha = best + et;
      if (lane < NLAB) bp8[s * 16 + lane] = (unsigned char)bi;
    }
    float fin = alpha + ((lane < NLAB) ? endv[lane] : 0.f);
    float fv[NLAB];
#pragma unroll
    for (int j = 0; j < NLAB; ++j) fv[j] = __shfl(fin, j);
    float f01 = (fv[0] >= fv[1]) ? fv[0] : fv[1];  int j01 = (fv[0] >= fv[1]) ? 0 : 1;
    float f23 = (fv[2] >= fv[3]) ? fv[2] : fv[3];  int j23 = (fv[2] >= fv[3]) ? 2 : 3;
    float f45 = (fv[4] >= fv[5]) ? fv[4] : fv[5];  int j45 = (fv[4] >= fv[5]) ? 4 : 5;
    float f67 = (fv[6] >= fv[7]) ? fv[6] : fv[7];  int j67 = (fv[6] >= fv[7]) ? 6 : 7;
    float fa = (f01 >= f23) ? f01 : f23;           int ja = (f01 >= f23) ? j01 : j23;
    float fb = (f45 >= f67) ? f45 : f67;           int jb = (f45 >= f67) ? j45 : j67;
    float fc = (fa >= fb) ? fa : fb;               int jc = (fa >= fb) ? ja : jb;
    int last = (fc >= fv[8]) ? jc : 8;
    if (lane == 0) {
      int y = last;
      dec_out[b * T_LEN + (T_LEN - 1)] = (float)y;
      uint4 row = *reinterpret_cast<const uint4*>(&bp8[(T_LEN - 2) * 16]);
      for (int s = T_LEN - 2; s >= 0; --s) {
        uint4 nrow = row;
        if (s > 0) nrow = *reinterpret_cast<const uint4*>(&bp8[(s - 1) * 16]);
        unsigned wsel = (y < 4) ? row.x : ((y < 8) ? row.y : row.z);
        y = (int)((wsel >> ((y & 3) * 8)) & 0xffu);
        dec_out[b * T_LEN + s] = (float)y;
        row = nrow;
      }
    }
  } else if (w == 1) {
    // ---- CRF log-likelihood ----
    float tcol[NLAB];
#pragma unroll
    for (int i = 0; i < NLAB; ++i)
      tcol[i] = (lane < NLAB) ? trans[i * NLAB + lane] : 0.f;
    float ca = (lane < NLAB) ? (start[lane] + el[lane]) : -3e38f;
    float et_next = (lane < NLAB) ? el[10 + lane] : 0.f;
    for (int s = 0; s < T_LEN - 1; ++s) {
      const float et = et_next;
      if (s < T_LEN - 2)
        et_next = (lane < NLAB) ? el[(s + 2) * 10 + lane] : 0.f;
      float c[NLAB];
#pragma unroll
      for (int i = 0; i < NLAB; ++i) c[i] = __shfl(ca, i) + tcol[i];
      float m01 = fmaxf(c[0], c[1]), m23 = fmaxf(c[2], c[3]);
      float m45 = fmaxf(c[4], c[5]), m67 = fmaxf(c[6], c[7]);
      float m = fmaxf(fmaxf(fmaxf(m01, m23), fmaxf(m45, m67)), c[8]);
      float p0 = expf(c[0]-m) + expf(c[1]-m), p1 = expf(c[2]-m) + expf(c[3]-m);
      float p2 = expf(c[4]-m) + expf(c[5]-m), p3 = expf(c[6]-m) + expf(c[7]-m);
      float p = ((p0 + p1) + (p2 + p3)) + expf(c[8]-m);
      ca = m + logf(p) + et;
    }
    float fv[NLAB]; float mx = -3e38f;
#pragma unroll
    for (int j = 0; j < NLAB; ++j) {
      fv[j] = __shfl(ca, j) + endv[j];
      mx = fmaxf(mx, fv[j]);
    }
    float ps = 0.f;
#pragma unroll
    for (int j = 0; j < NLAB; ++j) ps += expf(fv[j] - mx);
    float denom = mx + logf(ps);

    const int* lb = labels + b * T_LEN;
    float part = 0.f;
    for (int t4 = 0; t4 < 4; ++t4) {
      int t = lane * 4 + t4;
      int l = lb[t];
      part += el[t * 10 + l];
      if (t > 0) part += trans[lb[t - 1] * NLAB + l];
    }
#pragma unroll
    for (int off = 32; off > 0; off >>= 1) part += __shfl_xor(part, off);
    if (lane == 0) {
      float num = part + start[lb[0]] + endv[lb[T_LEN - 1]];
      float llh = num - denom;
      atomicAdd(lossp, -llh * (1.0f / BATCH));
    }
  }
}

extern "C" void kernel_launch(void* const* d_in, const int* in_sizes, int n_in,
                              void* d_out, int out_size, void* d_ws, size_t ws_size,
                              hipStream_t stream) {
  const int*   ids    = (const int*)d_in[0];
  const int*   labels = (const int*)d_in[2];
  const float* emb    = (const float*)d_in[3];
  const float* Wihf   = (const float*)d_in[4];
  const float* Whhf   = (const float*)d_in[5];
  const float* bihf   = (const float*)d_in[6];
  const float* bhhf   = (const float*)d_in[7];
  const float* Wihb   = (const float*)d_in[8];
  const float* Whhb   = (const float*)d_in[9];
  const float* bihb   = (const float*)d_in[10];
  const float* bhhb   = (const float*)d_in[11];
  const float* Wlin   = (const float*)d_in[12];
  const float* blin   = (const float*)d_in[13];
  const float* trans  = (const float*)d_in[14];
  const float* start  = (const float*)d_in[15];
  const float* endv   = (const float*)d_in[16];

  float* xp    = (float*)d_ws;                       // [T][B][768]
  float* hbuf  = xp + (size_t)M_TOT * HID;           // [T][B][256]
  float* out   = (float*)d_out;                      // decoded as floats
  float* lossp = out + M_TOT;                        // loss scalar

  k_gemm_xp<<<dim3(6, 64), 256, 0, stream>>>(ids, emb, Wihf, Wihb, bihf, bihb, xp);
  k_gru<<<64, 512, 0, stream>>>(xp, Whhf, Whhb, bhhf, bhhb, hbuf, lossp);
  k_crf_fused<<<BATCH, 256, 0, stream>>>(hbuf, Wlin, blin, labels, trans,
                                         start, endv, out, lossp);
}

// Round 10
// 417.980 us; speedup vs baseline: 1.1411x; 1.1411x over previous
//
#include <hip/hip_runtime.h>
#include <math.h>

#define T_LEN 256
#define BATCH 32
#define HID   768
#define GH    384   // 3*LSTM_H
#define LH    128   // LSTM_H
#define NLAB  9
#define M_TOT (T_LEN*BATCH)  // 8192

typedef float v2f __attribute__((ext_vector_type(2)));
typedef _Float16 h8 __attribute__((ext_vector_type(8)));
typedef float f4 __attribute__((ext_vector_type(4)));

#define LO_SCALE 1024.f
#define LO_INV   (1.f/1024.f)

// Immediate-pattern lane broadcast within 32-lane half: every lane reads lane i.
// (BitMode: and=0, or=i, xor=0 -> pattern = i<<5.)  No address VGPR, so 9 of
// these issue back-to-back with ONE lgkm wait (vs __shfl -> ds_bpermute chains).
// NOTE: pattern must be a compile-time literal -> only use with literal i.
#define BC(x, i) __int_as_float(__builtin_amdgcn_ds_swizzle(__float_as_int(x), (i) << 5))

// ---------------- K1: xp = emb[ids] @ [Wih_f;Wih_b]^T + bias  (MFMA v5) -----
// v5: next k-tile global loads prefetched into registers between LDS store and
// the second barrier -> load latency hidden behind the MFMA phase.
__global__ __launch_bounds__(256, 2) void k_gemm_xp(
    const int* __restrict__ ids, const float* __restrict__ emb,
    const float* __restrict__ Wf, const float* __restrict__ Wb,
    const float* __restrict__ bihf, const float* __restrict__ bihb,
    float* __restrict__ xp)
{
  __shared__ __align__(16) _Float16 Ah[128*40];
  __shared__ __align__(16) _Float16 Al[128*40];
  __shared__ __align__(16) _Float16 Bh[128*40];
  __shared__ __align__(16) _Float16 Bl[128*40];

  const int tid  = threadIdx.x;
  const int lane = tid & 63, w = tid >> 6;
  const int m0 = blockIdx.y * 128, n0 = blockIdx.x * 128;

  const int srow = tid >> 1, sk = (tid & 1) * 16;
  const int gm = m0 + srow;
  const int tok = ids[(gm & 31) * T_LEN + (gm >> 5)];
  const float* aG = emb + (size_t)tok * HID + sk;
  const int gn = n0 + srow;
  const float* bG = (gn < GH ? Wf + (size_t)gn * HID
                             : Wb + (size_t)(gn - GH) * HID) + sk;

  const int fr = lane & 15, fq = lane >> 4;
  const int mrow = (w & 1) * 64;
  const int ncol = (w >> 1) * 64;

  f4 acc[4][4];
  f4 acc2[4][4];
#pragma unroll
  for (int i = 0; i < 4; ++i)
#pragma unroll
    for (int j = 0; j < 4; ++j) { acc[i][j] = f4{0,0,0,0}; acc2[i][j] = f4{0,0,0,0}; }

  const int sb = srow * 40 + sk;

  float4 ra[4], rb[4];
#pragma unroll
  for (int c = 0; c < 4; ++c) {
    ra[c] = *reinterpret_cast<const float4*>(aG + 4 * c);
    rb[c] = *reinterpret_cast<const float4*>(bG + 4 * c);
  }

  for (int kt = 0; kt < HID / 32; ++kt) {
    __syncthreads();
    // convert current regs -> LDS (hi + scaled lo)
#pragma unroll
    for (int m = 0; m < 2; ++m) {
      const float4* src = m ? rb : ra;
      _Float16* dsth = m ? Bh : Ah;
      _Float16* dstl = m ? Bl : Al;
#pragma unroll
      for (int seg = 0; seg < 2; ++seg) {
        float xs[8] = {src[2*seg].x, src[2*seg].y, src[2*seg].z, src[2*seg].w,
                       src[2*seg+1].x, src[2*seg+1].y, src[2*seg+1].z, src[2*seg+1].w};
        h8 hi, lo;
#pragma unroll
        for (int c = 0; c < 8; ++c) {
          _Float16 h = (_Float16)xs[c];
          hi[c] = h;
          lo[c] = (_Float16)((xs[c] - (float)h) * LO_SCALE);
        }
        *reinterpret_cast<h8*>(&dsth[sb + seg * 8]) = hi;
        *reinterpret_cast<h8*>(&dstl[sb + seg * 8]) = lo;
      }
    }
    // prefetch next tile (latency hidden behind MFMA phase below)
    if (kt + 1 < HID / 32) {
      const float* pa = aG + (kt + 1) * 32;
      const float* pb = bG + (kt + 1) * 32;
#pragma unroll
      for (int c = 0; c < 4; ++c) {
        ra[c] = *reinterpret_cast<const float4*>(pa + 4 * c);
        rb[c] = *reinterpret_cast<const float4*>(pb + 4 * c);
      }
    }
    __syncthreads();

    h8 fbh[4], fbl[4];
#pragma unroll
    for (int j = 0; j < 4; ++j) {
      const int off = (ncol + j * 16 + fr) * 40 + fq * 8;
      fbh[j] = *reinterpret_cast<const h8*>(&Bh[off]);
      fbl[j] = *reinterpret_cast<const h8*>(&Bl[off]);
    }
#pragma unroll
    for (int i = 0; i < 4; ++i) {
      const int off = (mrow + i * 16 + fr) * 40 + fq * 8;
      h8 fah = *reinterpret_cast<const h8*>(&Ah[off]);
      h8 fal = *reinterpret_cast<const h8*>(&Al[off]);
#pragma unroll
      for (int j = 0; j < 4; ++j) {
        acc[i][j]  = __builtin_amdgcn_mfma_f32_16x16x32_f16(fah, fbh[j], acc[i][j],  0, 0, 0);
        acc2[i][j] = __builtin_amdgcn_mfma_f32_16x16x32_f16(fah, fbl[j], acc2[i][j], 0, 0, 0);
        acc2[i][j] = __builtin_amdgcn_mfma_f32_16x16x32_f16(fal, fbh[j], acc2[i][j], 0, 0, 0);
      }
    }
  }

  float bcol[4];
#pragma unroll
  for (int j = 0; j < 4; ++j) {
    const int c = n0 + ncol + j * 16 + fr;
    bcol[j] = (c < GH) ? bihf[c] : bihb[c - GH];
  }
#pragma unroll
  for (int i = 0; i < 4; ++i)
#pragma unroll
    for (int j = 0; j < 4; ++j) {
      const int col = n0 + ncol + j * 16 + fr;
#pragma unroll
      for (int r = 0; r < 4; ++r) {
        const int row = m0 + mrow + i * 16 + fq * 4 + r;
        xp[(size_t)row * HID + col] = acc[i][j][r] + acc2[i][j][r] * LO_INV + bcol[j];
      }
    }
}

// ---------------- K2: bidirectional GRU recurrence (v3 — frozen) ------------
__global__ __launch_bounds__(512, 2) void k_gru(
    const float* __restrict__ xp,
    const float* __restrict__ Whhf, const float* __restrict__ Whhb,
    const float* __restrict__ bhhf, const float* __restrict__ bhhb,
    float* __restrict__ hbuf, float* __restrict__ lossp)
{
  __shared__ __align__(16) float hsp[2][144];
  const int tid = threadIdx.x;
  const int g   = tid >> 2;
  const int q   = tid & 3;
  const int bd  = blockIdx.x;
  const int dir = bd >> 5, b = bd & 31;
  const float* Whh = dir ? Whhb : Whhf;
  const float* bhh = dir ? bhhb : bhhf;

  if (bd == 0 && tid == 0) *lossp = 0.f;

  v2f w[3][16];
#pragma unroll
  for (int gate = 0; gate < 3; ++gate) {
    const float* wrow = Whh + (size_t)(gate * LH + g) * LH + q * 32;
#pragma unroll
    for (int j = 0; j < 8; ++j) {
      float4 w4 = *reinterpret_cast<const float4*>(wrow + j * 4);
      w[gate][2*j]   = v2f{w4.x, w4.y};
      w[gate][2*j+1] = v2f{w4.z, w4.w};
    }
  }
  const float br = bhh[g], bz = bhh[g + LH], bn = bhh[g + 2*LH];

  if (tid < LH) hsp[0][36*(tid >> 5) + (tid & 31)] = 0.f;

  const int t0   = dir ? (T_LEN - 1) : 0;
  const int dt   = dir ? -1 : 1;
  const float* xbase = xp + (size_t)b * HID + dir * GH + g;
  float* hob = hbuf + (size_t)b * 256 + dir * LH + g;

  float xr = 0.f, xz = 0.f, xn = 0.f;
  if (q == 0) {
    const float* p = xbase + (size_t)t0 * BATCH * HID;
    xr = p[0]; xz = p[LH]; xn = p[2*LH];
  }
  float hprev = 0.f;
  __syncthreads();

  int t = t0;
  for (int step = 0; step < T_LEN; ++step) {
    const int tn = (step < T_LEN - 1) ? (t + dt) : t;
    float xrn = 0.f, xzn = 0.f, xnn = 0.f;
    if (q == 0) {
      const float* p = xbase + (size_t)tn * BATCH * HID;
      xrn = p[0]; xzn = p[LH]; xnn = p[2*LH];
    }

    const float* hc = &hsp[step & 1][36 * q];
    v2f ar0 = v2f{0.f,0.f}, ar1 = ar0, az0 = ar0, az1 = ar0, an0 = ar0, an1 = ar0;
#pragma unroll
    for (int j = 0; j < 4; ++j) {
      float4 ha = *reinterpret_cast<const float4*>(hc + 8*j);
      float4 hb = *reinterpret_cast<const float4*>(hc + 8*j + 4);
      v2f h0 = v2f{ha.x, ha.y}, h1 = v2f{ha.z, ha.w};
      v2f h2 = v2f{hb.x, hb.y}, h3 = v2f{hb.z, hb.w};
      ar0 = __builtin_elementwise_fma(w[0][4*j+0], h0, ar0);
      ar1 = __builtin_elementwise_fma(w[0][4*j+1], h1, ar1);
      ar0 = __builtin_elementwise_fma(w[0][4*j+2], h2, ar0);
      ar1 = __builtin_elementwise_fma(w[0][4*j+3], h3, ar1);
      az0 = __builtin_elementwise_fma(w[1][4*j+0], h0, az0);
      az1 = __builtin_elementwise_fma(w[1][4*j+1], h1, az1);
      az0 = __builtin_elementwise_fma(w[1][4*j+2], h2, az0);
      az1 = __builtin_elementwise_fma(w[1][4*j+3], h3, az1);
      an0 = __builtin_elementwise_fma(w[2][4*j+0], h0, an0);
      an1 = __builtin_elementwise_fma(w[2][4*j+1], h1, an1);
      an0 = __builtin_elementwise_fma(w[2][4*j+2], h2, an0);
      an1 = __builtin_elementwise_fma(w[2][4*j+3], h3, an1);
    }
    float ar = (ar0.x + ar0.y) + (ar1.x + ar1.y);
    float az = (az0.x + az0.y) + (az1.x + az1.y);
    float an = (an0.x + an0.y) + (an1.x + an1.y);
    ar += __shfl_xor(ar, 1);  ar += __shfl_xor(ar, 2);
    az += __shfl_xor(az, 1);  az += __shfl_xor(az, 2);
    an += __shfl_xor(an, 1);  an += __shfl_xor(an, 2);

    if (q == 0) {
      float r  = __builtin_amdgcn_rcpf(1.f + __expf(-(xr + ar + br)));
      float z  = __builtin_amdgcn_rcpf(1.f + __expf(-(xz + az + bz)));
      float e2 = __expf(2.f * (xn + r * (an + bn)));
      float n  = (e2 - 1.f) * __builtin_amdgcn_rcpf(e2 + 1.f);
      float hnew = (1.f - z) * n + z * hprev;
      hprev = hnew;
      hsp[(step + 1) & 1][36*(g >> 5) + (g & 31)] = hnew;
      hob[(size_t)t * BATCH * 256] = hnew;
    }
    __syncthreads();
    xr = xrn; xz = xzn; xn = xnn;
    t = tn;
  }
}

// ---------------- K3: fused emissions + Viterbi + CRF-LLH (v2) --------------
// 32 blocks (one per batch), 256 threads. Phase 2 all-gathers use immediate
// ds_swizzle broadcasts (no address-VGPR serialization); LLH uses __expf/__logf.
__global__ __launch_bounds__(256, 1) void k_crf_fused(
    const float* __restrict__ hbuf, const float* __restrict__ Wlin,
    const float* __restrict__ blin, const int* __restrict__ labels,
    const float* __restrict__ trans, const float* __restrict__ start,
    const float* __restrict__ endv, float* __restrict__ dec_out,
    float* __restrict__ lossp)
{
  __shared__ float el[T_LEN * 10];
  __shared__ __align__(16) unsigned char bp8[(T_LEN - 1) * 16];
  const int b    = blockIdx.x;
  const int tid  = threadIdx.x;
  const int lane = tid & 63, w = tid >> 6;
  const int sub  = lane >> 4, l16 = lane & 15;

  float4 wreg[NLAB][4];
#pragma unroll
  for (int j = 0; j < NLAB; ++j)
#pragma unroll
    for (int c = 0; c < 4; ++c)
      wreg[j][c] = *reinterpret_cast<const float4*>(Wlin + j * 256 + l16 * 16 + c * 4);

  // ---- phase 1: emissions ----
  for (int k = 0; k < 16; ++k) {
    const int t = w * 64 + k * 4 + sub;
    const float* hp = hbuf + ((size_t)t * BATCH + b) * 256 + l16 * 16;
    const float4 h0 = *reinterpret_cast<const float4*>(hp);
    const float4 h1 = *reinterpret_cast<const float4*>(hp + 4);
    const float4 h2 = *reinterpret_cast<const float4*>(hp + 8);
    const float4 h3 = *reinterpret_cast<const float4*>(hp + 12);
    float acc[NLAB];
#pragma unroll
    for (int j = 0; j < NLAB; ++j) {
      const float4 w0 = wreg[j][0], w1 = wreg[j][1], w2 = wreg[j][2], w3 = wreg[j][3];
      float s0 = h0.x*w0.x + h0.y*w0.y + h0.z*w0.z + h0.w*w0.w;
      float s1 = h1.x*w1.x + h1.y*w1.y + h1.z*w1.z + h1.w*w1.w;
      float s2 = h2.x*w2.x + h2.y*w2.y + h2.z*w2.z + h2.w*w2.w;
      float s3 = h3.x*w3.x + h3.y*w3.y + h3.z*w3.z + h3.w*w3.w;
      acc[j] = (s0 + s1) + (s2 + s3);
    }
#pragma unroll
    for (int j = 0; j < NLAB; ++j) {
#pragma unroll
      for (int off = 1; off < 16; off <<= 1)
        acc[j] += __shfl_xor(acc[j], off);
    }
    if (l16 < NLAB) {
      float v = acc[0];
#pragma unroll
      for (int j = 1; j < NLAB; ++j) v = (l16 == j) ? acc[j] : v;
      el[t * 10 + l16] = v + blin[l16];
    }
  }
  __syncthreads();

  if (w == 0) {
    // ---- Viterbi ----
    float tcol[NLAB];
#pragma unroll
    for (int i = 0; i < NLAB; ++i)
      tcol[i] = (lane < NLAB) ? trans[i * NLAB + lane] : 0.f;
    float alpha = (lane < NLAB) ? (start[lane] + el[lane]) : -3e38f;
    float et_next = (lane < NLAB) ? el[10 + lane] : 0.f;
    for (int s = 0; s < T_LEN - 1; ++s) {
      const float et = et_next;
      if (s < T_LEN - 2)
        et_next = (lane < NLAB) ? el[(s + 2) * 10 + lane] : 0.f;
      float v[NLAB];
      v[0] = BC(alpha, 0) + tcol[0];
      v[1] = BC(alpha, 1) + tcol[1];
      v[2] = BC(alpha, 2) + tcol[2];
      v[3] = BC(alpha, 3) + tcol[3];
      v[4] = BC(alpha, 4) + tcol[4];
      v[5] = BC(alpha, 5) + tcol[5];
      v[6] = BC(alpha, 6) + tcol[6];
      v[7] = BC(alpha, 7) + tcol[7];
      v[8] = BC(alpha, 8) + tcol[8];
      float v01 = (v[0] >= v[1]) ? v[0] : v[1];  int i01 = (v[0] >= v[1]) ? 0 : 1;
      float v23 = (v[2] >= v[3]) ? v[2] : v[3];  int i23 = (v[2] >= v[3]) ? 2 : 3;
      float v45 = (v[4] >= v[5]) ? v[4] : v[5];  int i45 = (v[4] >= v[5]) ? 4 : 5;
      float v67 = (v[6] >= v[7]) ? v[6] : v[7];  int i67 = (v[6] >= v[7]) ? 6 : 7;
      float va = (v01 >= v23) ? v01 : v23;       int ia = (v01 >= v23) ? i01 : i23;
      float vb = (v45 >= v67) ? v45 : v67;       int ib = (v45 >= v67) ? i45 : i67;
      float vc = (va >= vb) ? va : vb;           int ic = (va >= vb) ? ia : ib;
      float best = (vc >= v[8]) ? vc : v[8];     int bi = (vc >= v[8]) ? ic : 8;
      alpha = best + et;
      if (lane < NLAB) bp8[s * 16 + lane] = (unsigned char)bi;
    }
    float fin = alpha + ((lane < NLAB) ? endv[lane] : 0.f);
    float fv[NLAB];
    fv[0] = BC(fin, 0); fv[1] = BC(fin, 1); fv[2] = BC(fin, 2);
    fv[3] = BC(fin, 3); fv[4] = BC(fin, 4); fv[5] = BC(fin, 5);
    fv[6] = BC(fin, 6); fv[7] = BC(fin, 7); fv[8] = BC(fin, 8);
    float f01 = (fv[0] >= fv[1]) ? fv[0] : fv[1];  int j01 = (fv[0] >= fv[1]) ? 0 : 1;
    float f23 = (fv[2] >= fv[3]) ? fv[2] : fv[3];  int j23 = (fv[2] >= fv[3]) ? 2 : 3;
    float f45 = (fv[4] >= fv[5]) ? fv[4] : fv[5];  int j45 = (fv[4] >= fv[5]) ? 4 : 5;
    float f67 = (fv[6] >= fv[7]) ? fv[6] : fv[7];  int j67 = (fv[6] >= fv[7]) ? 6 : 7;
    float fa = (f01 >= f23) ? f01 : f23;           int ja = (f01 >= f23) ? j01 : j23;
    float fb = (f45 >= f67) ? f45 : f67;           int jb = (f45 >= f67) ? j45 : j67;
    float fc = (fa >= fb) ? fa : fb;               int jc = (fa >= fb) ? ja : jb;
    int last = (fc >= fv[8]) ? jc : 8;
    if (lane == 0) {
      int y = last;
      dec_out[b * T_LEN + (T_LEN - 1)] = (float)y;
      uint4 row = *reinterpret_cast<const uint4*>(&bp8[(T_LEN - 2) * 16]);
      for (int s = T_LEN - 2; s >= 0; --s) {
        uint4 nrow = row;
        if (s > 0) nrow = *reinterpret_cast<const uint4*>(&bp8[(s - 1) * 16]);
        unsigned wsel = (y < 4) ? row.x : ((y < 8) ? row.y : row.z);
        y = (int)((wsel >> ((y & 3) * 8)) & 0xffu);
        dec_out[b * T_LEN + s] = (float)y;
        row = nrow;
      }
    }
  } else if (w == 1) {
    // ---- CRF log-likelihood ----
    float tcol[NLAB];
#pragma unroll
    for (int i = 0; i < NLAB; ++i)
      tcol[i] = (lane < NLAB) ? trans[i * NLAB + lane] : 0.f;
    float ca = (lane < NLAB) ? (start[lane] + el[lane]) : -3e38f;
    float et_next = (lane < NLAB) ? el[10 + lane] : 0.f;
    for (int s = 0; s < T_LEN - 1; ++s) {
      const float et = et_next;
      if (s < T_LEN - 2)
        et_next = (lane < NLAB) ? el[(s + 2) * 10 + lane] : 0.f;
      float c[NLAB];
      c[0] = BC(ca, 0) + tcol[0];
      c[1] = BC(ca, 1) + tcol[1];
      c[2] = BC(ca, 2) + tcol[2];
      c[3] = BC(ca, 3) + tcol[3];
      c[4] = BC(ca, 4) + tcol[4];
      c[5] = BC(ca, 5) + tcol[5];
      c[6] = BC(ca, 6) + tcol[6];
      c[7] = BC(ca, 7) + tcol[7];
      c[8] = BC(ca, 8) + tcol[8];
      float m01 = fmaxf(c[0], c[1]), m23 = fmaxf(c[2], c[3]);
      float m45 = fmaxf(c[4], c[5]), m67 = fmaxf(c[6], c[7]);
      float m = fmaxf(fmaxf(fmaxf(m01, m23), fmaxf(m45, m67)), c[8]);
      float p0 = __expf(c[0]-m) + __expf(c[1]-m), p1 = __expf(c[2]-m) + __expf(c[3]-m);
      float p2 = __expf(c[4]-m) + __expf(c[5]-m), p3 = __expf(c[6]-m) + __expf(c[7]-m);
      float p = ((p0 + p1) + (p2 + p3)) + __expf(c[8]-m);
      ca = m + __logf(p) + et;
    }
    float fv[NLAB];
    fv[0] = BC(ca, 0) + endv[0];
    fv[1] = BC(ca, 1) + endv[1];
    fv[2] = BC(ca, 2) + endv[2];
    fv[3] = BC(ca, 3) + endv[3];
    fv[4] = BC(ca, 4) + endv[4];
    fv[5] = BC(ca, 5) + endv[5];
    fv[6] = BC(ca, 6) + endv[6];
    fv[7] = BC(ca, 7) + endv[7];
    fv[8] = BC(ca, 8) + endv[8];
    float mx = -3e38f;
#pragma unroll
    for (int j = 0; j < NLAB; ++j) mx = fmaxf(mx, fv[j]);
    float ps = 0.f;
#pragma unroll
    for (int j = 0; j < NLAB; ++j) ps += __expf(fv[j] - mx);
    float denom = mx + __logf(ps);

    const int* lb = labels + b * T_LEN;
    float part = 0.f;
    for (int t4 = 0; t4 < 4; ++t4) {
      int t = lane * 4 + t4;
      int l = lb[t];
      part += el[t * 10 + l];
      if (t > 0) part += trans[lb[t - 1] * NLAB + l];
    }
#pragma unroll
    for (int off = 32; off > 0; off >>= 1) part += __shfl_xor(part, off);
    if (lane == 0) {
      float num = part + start[lb[0]] + endv[lb[T_LEN - 1]];
      float llh = num - denom;
      atomicAdd(lossp, -llh * (1.0f / BATCH));
    }
  }
}

extern "C" void kernel_launch(void* const* d_in, const int* in_sizes, int n_in,
                              void* d_out, int out_size, void* d_ws, size_t ws_size,
                              hipStream_t stream) {
  const int*   ids    = (const int*)d_in[0];
  const int*   labels = (const int*)d_in[2];
  const float* emb    = (const float*)d_in[3];
  const float* Wihf   = (const float*)d_in[4];
  const float* Whhf   = (const float*)d_in[5];
  const float* bihf   = (const float*)d_in[6];
  const float* bhhf   = (const float*)d_in[7];
  const float* Wihb   = (const float*)d_in[8];
  const float* Whhb   = (const float*)d_in[9];
  const float* bihb   = (const float*)d_in[10];
  const float* bhhb   = (const float*)d_in[11];
  const float* Wlin   = (const float*)d_in[12];
  const float* blin   = (const float*)d_in[13];
  const float* trans  = (const float*)d_in[14];
  const float* start  = (const float*)d_in[15];
  const float* endv   = (const float*)d_in[16];

  float* xp    = (float*)d_ws;                       // [T][B][768]
  float* hbuf  = xp + (size_t)M_TOT * HID;           // [T][B][256]
  float* out   = (float*)d_out;                      // decoded as floats
  float* lossp = out + M_TOT;                        // loss scalar

  k_gemm_xp<<<dim3(6, 64), 256, 0, stream>>>(ids, emb, Wihf, Wihb, bihf, bihb, xp);
  k_gru<<<64, 512, 0, stream>>>(xp, Whhf, Whhb, bhhf, bhhb, hbuf, lossp);
  k_crf_fused<<<BATCH, 256, 0, stream>>>(hbuf, Wlin, blin, labels, trans,
                                         start, endv, out, lossp);
}